// Round 6
// baseline (269.032 us; speedup 1.0000x reference)
//
#include <hip/hip_runtime.h>

// B=8, L=128, R=2048, E=32, F=64
#define NB 8
#define NL 128
#define NR 2048
#define NE 32
#define NF 64

typedef __attribute__((ext_vector_type(4)))  float f32x4;
typedef __attribute__((ext_vector_type(16))) float f32x16;
typedef __attribute__((ext_vector_type(8)))  short s16x8;
typedef __attribute__((ext_vector_type(2)))  unsigned int u32x2;

// (bf16(b) << 16) | bf16(a), round-half-up: +0x8000 then byte-select
__device__ __forceinline__ unsigned bf16pair(float a, float b) {
    union { float f; unsigned u; } ua, ub; ua.f = a; ub.f = b;
    return __builtin_amdgcn_perm(ub.u + 0x8000u, ua.u + 0x8000u, 0x07060302u);
}

__device__ __forceinline__ u32x2 pack4(f32x4 v) {
    u32x2 r;
    r.x = bf16pair(v.x, v.y);
    r.y = bf16pair(v.z, v.w);
    return r;
}

// One wave per block. Wave-private LDS tiles -> ZERO __syncthreads in main loop.
// 12 waves/CU (launch_bounds 3/SIMD), ~8.2 KB LDS/block.
__global__ __launch_bounds__(64, 3) void ff_kernel(
    const float* __restrict__ lig_feat,
    const float* __restrict__ rec_feat,
    const float* __restrict__ lig_coord,
    const float* __restrict__ rec_coord,
    float* __restrict__ out)
{
    // bf16 tiles, 32 rows x 64 f; rows of 8 x 16B chunks, chunk XOR-swizzled by (row&7)
    __shared__ __align__(16) unsigned short sA[32 * NF];   // 4 KB
    __shared__ __align__(16) unsigned short sB[32 * NF];   // 4 KB

    // task: (b, l-strip 32, r-strip 32, e-half 16)
    const int blk = blockIdx.x;
    const int eh  = blk & 1;
    const int lt  = (blk >> 1) & 3;
    const int rt  = (blk >> 3) & 63;       // consecutive blocks share rec strip
    const int b   = blk >> 9;              // 8*64*4*2 = 4096 blocks
    const int e0  = eh * 16;
    const int l0  = lt * 32;
    const int r0  = rt * 32;
    const int lane = threadIdx.x;
    const int n = lane & 31;
    const int h = lane >> 5;

    // per-lane load pattern: f4 = 16B column, rows row0+4j (j=0..7)
    const int f4   = lane & 15;
    const int row0 = lane >> 4;            // 0..3

    const float* baseA = lig_feat + (((long)b * NL + l0) * NE + e0) * NF + f4 * 4;
    const float* baseB = rec_feat + (((long)b * NR + r0) * NE + e0) * NF + f4 * 4;

    // ---- prefetch e0 into registers ----
    f32x4 pA[8], pB[8];
    #pragma unroll
    for (int j = 0; j < 8; ++j)
        pA[j] = *(const f32x4*)(baseA + (long)(row0 + 4 * j) * (NE * NF));
    #pragma unroll
    for (int j = 0; j < 8; ++j)
        pB[j] = *(const f32x4*)(baseB + (long)(row0 + 4 * j) * (NE * NF));

    // ---- distances for this lane's 16 C elements (computed once) ----
    const int colr = r0 + n;
    const float rx = rec_coord[((long)b * NR + colr) * 3 + 0];
    const float ry = rec_coord[((long)b * NR + colr) * 3 + 1];
    const float rz = rec_coord[((long)b * NR + colr) * 3 + 2];
    float d[16];
    #pragma unroll
    for (int i = 0; i < 16; ++i) {
        const int row = l0 + 4 * h + (i & 3) + ((i >> 2) << 3);
        const float dx = lig_coord[((long)b * NL + row) * 3 + 0] - rx;
        const float dy = lig_coord[((long)b * NL + row) * 3 + 1] - ry;
        const float dz = lig_coord[((long)b * NL + row) * 3 + 2] - rz;
        d[i] = sqrtf(dx * dx + dy * dy + dz * dz);
    }

    const float inv_s = 32.0f / 12.0f;     // |1/sigma|
    const int sw = n & 7;
    const int fragRow = n * NF;

    float sum = 0.0f;

    // ---- e-loop: fully unrolled so next-e loads fold into offset: immediates ----
    #pragma unroll
    for (int ei = 0; ei < 16; ++ei) {
        // 1. convert + write current e's regs into wave-private LDS
        #pragma unroll
        for (int j = 0; j < 8; ++j) {
            const int r = row0 + 4 * j;
            const int pos = (((f4 >> 1) ^ (r & 7)) << 3) + ((f4 & 1) << 2);
            *(u32x2*)&sA[r * NF + pos] = pack4(pA[j]);
        }
        #pragma unroll
        for (int j = 0; j < 8; ++j) {
            const int r = row0 + 4 * j;
            const int pos = (((f4 >> 1) ^ (r & 7)) << 3) + ((f4 & 1) << 2);
            *(u32x2*)&sB[r * NF + pos] = pack4(pB[j]);
        }
        // 2. issue next-e global loads (consumed next iteration -> latency hidden)
        if (ei + 1 < 16) {
            #pragma unroll
            for (int j = 0; j < 8; ++j)
                pA[j] = *(const f32x4*)(baseA + (long)(row0 + 4 * j) * (NE * NF) + (ei + 1) * NF);
            #pragma unroll
            for (int j = 0; j < 8; ++j)
                pB[j] = *(const f32x4*)(baseB + (long)(row0 + 4 * j) * (NE * NF) + (ei + 1) * NF);
        }
        // 3. fragments + MFMA (reads wave-own LDS writes; lgkmcnt-ordered, no barrier)
        f32x16 acc = {0,0,0,0,0,0,0,0,0,0,0,0,0,0,0,0};
        #pragma unroll
        for (int kc = 0; kc < 4; ++kc) {
            const int off = (((kc * 2 + h) ^ sw) << 3);
            const s16x8 af = *(const s16x8*)&sA[fragRow + off];
            const s16x8 bf = *(const s16x8*)&sB[fragRow + off];
            acc = __builtin_amdgcn_mfma_f32_32x32x16_bf16(af, bf, acc, 0, 0, 0);
        }
        // 4. epilogue: z = d/|s| - mu/|s|, mu_e/|s| = e * (12/31)*(32/12) = e*32/31
        const float nmu = -(float)(e0 + ei) * (32.0f / 31.0f);
        #pragma unroll
        for (int i = 0; i < 16; ++i) {
            const float z = __builtin_fmaf(d[i], inv_s, nmu);
            sum += __expf(-z * z) * acc[i];
        }
    }

    // ---- wave reduce -> one atomic per block ----
    sum *= 0.01f;   // ENERGY_SCALE
    #pragma unroll
    for (int off = 32; off > 0; off >>= 1)
        sum += __shfl_down(sum, off, 64);
    if (lane == 0) atomicAdd(&out[b], sum);
}

extern "C" void kernel_launch(void* const* d_in, const int* in_sizes, int n_in,
                              void* d_out, int out_size, void* d_ws, size_t ws_size,
                              hipStream_t stream) {
    const float* lig_feat  = (const float*)d_in[0];
    const float* rec_feat  = (const float*)d_in[1];
    const float* lig_coord = (const float*)d_in[2];
    const float* rec_coord = (const float*)d_in[3];
    float* out = (float*)d_out;

    hipMemsetAsync(out, 0, (size_t)out_size * sizeof(float), stream);

    dim3 grid(NB * 64 * 4 * 2);   // 4096 single-wave blocks: (b, r-strip, l-strip, e-half)
    ff_kernel<<<grid, 64, 0, stream>>>(lig_feat, rec_feat,
                                       lig_coord, rec_coord, out);
}

// Round 7
// 207.141 us; speedup vs baseline: 1.2988x; 1.2988x over previous
//
#include <hip/hip_runtime.h>

// B=8, L=128, R=2048, E=32, F=64
#define NB 8
#define NL 128
#define NR 2048
#define NE 32
#define NF 64
#define RT 128                // r-rows per block
#define NRT (NR / RT)         // 16 r-tiles
#define EH 4                  // e-groups (blocks) per (b, rt)
#define EPB (NE / EH)         // 8 e's per block
#define NTHREADS 512
#define NWAVES (NTHREADS / 64)

typedef __attribute__((ext_vector_type(4)))  float f32x4;
typedef __attribute__((ext_vector_type(16))) float f32x16;
typedef __attribute__((ext_vector_type(8)))  short s16x8;
typedef __attribute__((ext_vector_type(2)))  unsigned int u32x2;

// (bf16(b) << 16) | bf16(a), round-half-up: +0x8000 then byte-select
__device__ __forceinline__ unsigned bf16pair(float a, float b) {
    union { float f; unsigned u; } ua, ub; ua.f = a; ub.f = b;
    return __builtin_amdgcn_perm(ub.u + 0x8000u, ua.u + 0x8000u, 0x07060302u);
}

__device__ __forceinline__ u32x2 pack4(f32x4 v) {
    u32x2 r;
    r.x = bf16pair(v.x, v.y);
    r.y = bf16pair(v.z, v.w);
    return r;
}

// Load the compiler cannot sink: issues exactly where placed.
__device__ __forceinline__ void async_load4(f32x4& r, const float* p) {
    asm volatile("global_load_dwordx4 %0, %1, off" : "=v"(r) : "v"(p) : "memory");
}

__global__ __launch_bounds__(NTHREADS, 2) void ff_kernel(
    const float* __restrict__ lig_feat,
    const float* __restrict__ rec_feat,
    const float* __restrict__ lig_coord,
    const float* __restrict__ rec_coord,
    float* __restrict__ out)
{
    // bf16 tiles; rows of 64 elems = 8 x 16B chunks, chunk XOR-swizzled by (row&7)
    __shared__ __align__(16) unsigned short sA[2][NL * NF];  // 2 x 16 KB
    __shared__ __align__(16) unsigned short sB[2][RT * NF];  // 2 x 16 KB
    __shared__ float sLc[3][NL];
    __shared__ float sRc[3][RT];
    __shared__ float sRed[NWAVES];

    const int blk = blockIdx.x;
    const int eh  = blk & (EH - 1);
    const int rt  = (blk >> 2) & (NRT - 1);
    const int b   = blk >> 6;            // 8*16*4 = 512 blocks
    const int e0  = eh * EPB;
    const int r0  = rt * RT;
    const int t   = threadIdx.x;
    const int lane = t & 63;
    const int wv   = t >> 6;

    // per-thread load pattern: f4 = 16B column (const), rows lrow0+32j / rrow0+32j
    const int f4    = t & 15;
    const int row00 = t >> 4;            // 0..31

    // ---- coords to LDS ----
    for (int i = t; i < 3 * NL; i += NTHREADS) {
        const int c = i >> 7, l = i & 127;
        sLc[c][l] = lig_coord[((long)b * NL + l) * 3 + c];
    }
    for (int i = t; i < 3 * RT; i += NTHREADS) {
        const int c = i >> 7, r = i & 127;
        sRc[c][r] = rec_coord[((long)b * NR + r0 + r) * 3 + c];
    }

    // ---- load e0 with normal loads (prologue only) ----
    f32x4 tA[4], tB[4];
    #pragma unroll
    for (int j = 0; j < 4; ++j)
        tA[j] = *(const f32x4*)(lig_feat + (((long)b * NL + (row00 + 32 * j)) * NE + e0) * NF + f4 * 4);
    #pragma unroll
    for (int j = 0; j < 4; ++j)
        tB[j] = *(const f32x4*)(rec_feat + (((long)b * NR + r0 + (row00 + 32 * j)) * NE + e0) * NF + f4 * 4);

    __syncthreads();   // coords visible

    // ---- distances once, kept in registers (2 tiles: tl0, tl0+2) ----
    const int n  = lane & 31;
    const int h  = lane >> 5;
    const int tr  = wv & 3;              // 0..3 over RT/32
    const int tl0 = wv >> 2;             // 0..1; tiles tl0 and tl0+2
    const int colr = tr * 32 + n;
    const float rx = sRc[0][colr], ry = sRc[1][colr], rz = sRc[2][colr];
    float d[2][16];
    #pragma unroll
    for (int t2 = 0; t2 < 2; ++t2) {
        const int tl = tl0 + 2 * t2;
        #pragma unroll
        for (int i = 0; i < 16; ++i) {
            const int row = tl * 32 + 4 * h + (i & 3) + ((i >> 2) << 3);
            const float dx = sLc[0][row] - rx;
            const float dy = sLc[1][row] - ry;
            const float dz = sLc[2][row] - rz;
            d[t2][i] = sqrtf(dx * dx + dy * dy + dz * dz);
        }
    }

    // ---- write e0 -> buf0; issue e1 asm loads; barrier ----
    #pragma unroll
    for (int j = 0; j < 4; ++j) {
        const int r = row00 + 32 * j;
        const int pos = (((f4 >> 1) ^ (r & 7)) << 3) + ((f4 & 1) << 2);
        *(u32x2*)&sA[0][r * NF + pos] = pack4(tA[j]);
    }
    #pragma unroll
    for (int j = 0; j < 4; ++j) {
        const int r = row00 + 32 * j;
        const int pos = (((f4 >> 1) ^ (r & 7)) << 3) + ((f4 & 1) << 2);
        *(u32x2*)&sB[0][r * NF + pos] = pack4(tB[j]);
    }
    if (EPB > 1) {
        #pragma unroll
        for (int j = 0; j < 4; ++j)
            async_load4(tA[j], lig_feat + (((long)b * NL + (row00 + 32 * j)) * NE + e0 + 1) * NF + f4 * 4);
        #pragma unroll
        for (int j = 0; j < 4; ++j)
            async_load4(tB[j], rec_feat + (((long)b * NR + r0 + (row00 + 32 * j)) * NE + e0 + 1) * NF + f4 * 4);
    }
    __syncthreads();   // buf0 visible; e1 loads remain in flight

    const float inv_s = 32.0f / 12.0f;       // |1/sigma|
    const int sw = n & 7;
    const int aRow = (tl0 * 32 + n) * NF;    // tile1 at +64*NF
    const int bRow = (tr * 32 + n) * NF;

    float sum = 0.0f;

    #pragma unroll
    for (int ep = 0; ep < EPB; ++ep) {
        const int cur = ep & 1;

        // -- compute on buf[cur]: pure LDS + VALU + MFMA, no vmem waits --
        f32x16 acc0 = {0,0,0,0,0,0,0,0,0,0,0,0,0,0,0,0};
        f32x16 acc1 = acc0;
        #pragma unroll
        for (int kc = 0; kc < 4; ++kc) {
            const int off = (((kc * 2 + h) ^ sw) << 3);
            const s16x8 a0 = *(const s16x8*)&sA[cur][aRow + off];
            const s16x8 a1 = *(const s16x8*)&sA[cur][aRow + 64 * NF + off];
            const s16x8 bf = *(const s16x8*)&sB[cur][bRow + off];
            acc0 = __builtin_amdgcn_mfma_f32_32x32x16_bf16(a0, bf, acc0, 0, 0, 0);
            acc1 = __builtin_amdgcn_mfma_f32_32x32x16_bf16(a1, bf, acc1, 0, 0, 0);
        }
        const float nmu = -(float)(e0 + ep) * (32.0f / 31.0f);  // mu_e/|s|
        #pragma unroll
        for (int i = 0; i < 16; ++i) {
            float z;
            z = __builtin_fmaf(d[0][i], inv_s, nmu); sum += __expf(-z * z) * acc0[i];
            z = __builtin_fmaf(d[1][i], inv_s, nmu); sum += __expf(-z * z) * acc1[i];
        }

        if (ep + 1 < EPB) {
            // -- wait for e_{ep+1} loads (issued a full compute phase ago);
            //    tie the registers so converts cannot hoist above the wait --
            asm volatile("s_waitcnt vmcnt(0)"
                         : "+v"(tA[0]), "+v"(tA[1]), "+v"(tA[2]), "+v"(tA[3]),
                           "+v"(tB[0]), "+v"(tB[1]), "+v"(tB[2]), "+v"(tB[3])
                         :: "memory");
            // -- convert + write e_{ep+1} into buf[cur^1] --
            #pragma unroll
            for (int j = 0; j < 4; ++j) {
                const int r = row00 + 32 * j;
                const int pos = (((f4 >> 1) ^ (r & 7)) << 3) + ((f4 & 1) << 2);
                *(u32x2*)&sA[cur ^ 1][r * NF + pos] = pack4(tA[j]);
            }
            #pragma unroll
            for (int j = 0; j < 4; ++j) {
                const int r = row00 + 32 * j;
                const int pos = (((f4 >> 1) ^ (r & 7)) << 3) + ((f4 & 1) << 2);
                *(u32x2*)&sB[cur ^ 1][r * NF + pos] = pack4(tB[j]);
            }
            // -- issue e_{ep+2} loads; they cross the barrier below --
            if (ep + 2 < EPB) {
                const int en = e0 + ep + 2;
                #pragma unroll
                for (int j = 0; j < 4; ++j)
                    async_load4(tA[j], lig_feat + (((long)b * NL + (row00 + 32 * j)) * NE + en) * NF + f4 * 4);
                #pragma unroll
                for (int j = 0; j < 4; ++j)
                    async_load4(tB[j], rec_feat + (((long)b * NR + r0 + (row00 + 32 * j)) * NE + en) * NF + f4 * 4);
            }
            __syncthreads();   // lgkm drain for ds_writes; asm loads stay in flight
        }
    }

    // ---- reduce: wave -> block -> global atomic ----
    sum *= 0.01f;   // ENERGY_SCALE
    #pragma unroll
    for (int off = 32; off > 0; off >>= 1)
        sum += __shfl_down(sum, off, 64);
    if (lane == 0) sRed[wv] = sum;
    __syncthreads();
    if (t == 0) {
        float s = 0.f;
        #pragma unroll
        for (int w = 0; w < NWAVES; ++w) s += sRed[w];
        atomicAdd(&out[b], s);
    }
}

extern "C" void kernel_launch(void* const* d_in, const int* in_sizes, int n_in,
                              void* d_out, int out_size, void* d_ws, size_t ws_size,
                              hipStream_t stream) {
    const float* lig_feat  = (const float*)d_in[0];
    const float* rec_feat  = (const float*)d_in[1];
    const float* lig_coord = (const float*)d_in[2];
    const float* rec_coord = (const float*)d_in[3];
    float* out = (float*)d_out;

    hipMemsetAsync(out, 0, (size_t)out_size * sizeof(float), stream);

    dim3 grid(NB * NRT * EH);   // 512 blocks: (b, r-tile, e-group)
    ff_kernel<<<grid, NTHREADS, 0, stream>>>(lig_feat, rec_feat,
                                             lig_coord, rec_coord, out);
}